// Round 1
// baseline (343.743 us; speedup 1.0000x reference)
//
#include <hip/hip_runtime.h>
#include <hip/hip_bf16.h>

#define B_ 4
#define S_ 4096
#define D_ 128

typedef __attribute__((ext_vector_type(8))) short bf16x8;   // 8 bf16 in 4 VGPRs
typedef __attribute__((ext_vector_type(4))) float f32x4;

static __device__ __forceinline__ unsigned short f2bf(float f) {
    // round-to-nearest-even float -> bf16
    unsigned int u = __float_as_uint(f);
    unsigned int r = (u + 0x7FFFu + ((u >> 16) & 1u)) >> 16;
    return (unsigned short)r;
}

// ---------------------------------------------------------------------------
// Kernel A: QKV projection.  X[16384][128] f32, W[128][128] f32 each.
// Writes Qw,Kw row-major bf16 [16384][128]; Vt transposed bf16 [B][128][4096].
// grid = 256 blocks x 256 threads; each block does 64 rows.
// ---------------------------------------------------------------------------
__global__ __launch_bounds__(256) void qkv_proj(
    const float* __restrict__ X,
    const float* __restrict__ Wq, const float* __restrict__ Wk,
    const float* __restrict__ Wv,
    unsigned short* __restrict__ Qw, unsigned short* __restrict__ Kw,
    unsigned short* __restrict__ Vt)
{
    __shared__ alignas(16) unsigned short Xs[64][136];   // 64 rows x 128 (+8 pad)
    __shared__ alignas(16) unsigned short Wt[128][136];  // W transposed [d_out][d_in]

    const int tid  = threadIdx.x;
    const int wave = tid >> 6, lane = tid & 63;
    const int lrow = lane & 15, lk = lane >> 4;
    const long r0  = (long)blockIdx.x * 64;   // global row base

    // stage X tile -> bf16 LDS (coalesced float4 reads)
    for (int i = tid; i < 2048; i += 256) {
        const int s = i >> 5, c4 = (i & 31) * 4;
        const float4 v = *(const float4*)(X + (r0 + s) * D_ + c4);
        Xs[s][c4 + 0] = f2bf(v.x); Xs[s][c4 + 1] = f2bf(v.y);
        Xs[s][c4 + 2] = f2bf(v.z); Xs[s][c4 + 3] = f2bf(v.w);
    }
    __syncthreads();

    // A-fragments: lane holds X[wave*16 + (lane&15)][kc*32 + (lane>>4)*8 + 0..7]
    bf16x8 af[4];
#pragma unroll
    for (int kc = 0; kc < 4; ++kc)
        af[kc] = *(const bf16x8*)&Xs[wave * 16 + lrow][kc * 32 + lk * 8];

    float vacc[8][4];   // V result parked in registers (Wt LDS gets reused)

#pragma unroll
    for (int w = 0; w < 3; ++w) {
        const float* W = (w == 0) ? Wq : (w == 1) ? Wk : Wv;
        // load W transposed: Wt[d_out][d_in]
        for (int i = tid; i < 16384; i += 256) {
            const int rr = i >> 7, cc = i & 127;
            Wt[cc][rr] = f2bf(W[i]);
        }
        __syncthreads();

#pragma unroll
        for (int nsub = 0; nsub < 8; ++nsub) {
            f32x4 acc = {0.f, 0.f, 0.f, 0.f};
#pragma unroll
            for (int kc = 0; kc < 4; ++kc) {
                const bf16x8 bf = *(const bf16x8*)&Wt[nsub * 16 + lrow][kc * 32 + lk * 8];
                acc = __builtin_amdgcn_mfma_f32_16x16x32_bf16(af[kc], bf, acc, 0, 0, 0);
            }
            if (w < 2) {
                unsigned short* dst = (w == 0) ? Qw : Kw;
#pragma unroll
                for (int r = 0; r < 4; ++r) {
                    const long row = r0 + wave * 16 + lk * 4 + r;
                    dst[row * D_ + nsub * 16 + lrow] = f2bf(acc[r]);
                }
            } else {
#pragma unroll
                for (int r = 0; r < 4; ++r) vacc[nsub][r] = acc[r];
            }
        }
        __syncthreads();   // all waves done reading Wt before reload / reuse
    }

    // V: bounce through LDS (reuse Wt region) for a coalesced transposed store
    unsigned short (*Vs)[136] = Wt;
#pragma unroll
    for (int nsub = 0; nsub < 8; ++nsub)
#pragma unroll
        for (int r = 0; r < 4; ++r)
            Vs[wave * 16 + lk * 4 + r][nsub * 16 + lrow] = f2bf(vacc[nsub][r]);
    __syncthreads();

    const int batch = (int)(r0 >> 12);
    const int sbase = (int)(r0 & 4095);
    const int dd = tid >> 1, sh = (tid & 1) * 32;
    unsigned short* vdst = Vt + (size_t)batch * D_ * S_ + (size_t)dd * S_ + sbase + sh;
    for (int j = 0; j < 32; ++j) vdst[j] = Vs[sh + j][dd];
}

// ---------------------------------------------------------------------------
// Kernel B: flash attention forward.  grid = (S/64, B), 256 threads (4 waves).
// Each wave owns 16 q-rows; KV tiles of 64; online softmax in fp32.
// ---------------------------------------------------------------------------
__global__ __launch_bounds__(256) void attn_fwd(
    const unsigned short* __restrict__ Qw, const unsigned short* __restrict__ Kw,
    const unsigned short* __restrict__ Vt, float* __restrict__ out)
{
    __shared__ alignas(16) unsigned short P_lds[4][16][72]; // per-wave private

    const int tid  = threadIdx.x;
    const int wave = tid >> 6, lane = tid & 63;
    const int lrow = lane & 15, lk = lane >> 4;
    const int b  = blockIdx.y;
    const int q0 = blockIdx.x * 64 + wave * 16;   // row within batch

    const unsigned short* Qb = Qw + (size_t)b * S_ * D_;
    const unsigned short* Kb = Kw + (size_t)b * S_ * D_;
    const unsigned short* Vb = Vt + (size_t)b * D_ * S_;

    // Q fragments (held for the whole kernel)
    bf16x8 qf[4];
#pragma unroll
    for (int kc = 0; kc < 4; ++kc)
        qf[kc] = *(const bf16x8*)&Qb[(size_t)(q0 + lrow) * D_ + kc * 32 + lk * 8];

    f32x4 oacc[8];
#pragma unroll
    for (int i = 0; i < 8; ++i) oacc[i] = (f32x4){0.f, 0.f, 0.f, 0.f};
    float m[4], l[4];
#pragma unroll
    for (int r = 0; r < 4; ++r) { m[r] = -1e30f; l[r] = 0.f; }

    const float scale = 0.08838834764831845f;   // 1/sqrt(128)

    for (int kv0 = 0; kv0 < S_; kv0 += 64) {
        // ---- S tile = Q @ K^T : 16 q-rows x 64 keys per wave ----
        f32x4 sacc[4];
#pragma unroll
        for (int n = 0; n < 4; ++n) sacc[n] = (f32x4){0.f, 0.f, 0.f, 0.f};
#pragma unroll
        for (int n = 0; n < 4; ++n) {
#pragma unroll
            for (int kc = 0; kc < 4; ++kc) {
                const bf16x8 kf = *(const bf16x8*)
                    &Kb[(size_t)(kv0 + n * 16 + lrow) * D_ + kc * 32 + lk * 8];
                sacc[n] = __builtin_amdgcn_mfma_f32_16x16x32_bf16(qf[kc], kf, sacc[n], 0, 0, 0);
            }
        }
        // ---- online softmax (stats live on rows (lk*4+r), replicated over 16 lanes) ----
        float tmax[4];
#pragma unroll
        for (int r = 0; r < 4; ++r)
            tmax[r] = fmaxf(fmaxf(sacc[0][r], sacc[1][r]),
                            fmaxf(sacc[2][r], sacc[3][r])) * scale;
#pragma unroll
        for (int mask = 1; mask <= 8; mask <<= 1)
#pragma unroll
            for (int r = 0; r < 4; ++r)
                tmax[r] = fmaxf(tmax[r], __shfl_xor(tmax[r], mask, 64));

        float corr[4], tsum[4];
#pragma unroll
        for (int r = 0; r < 4; ++r) {
            const float mn = fmaxf(m[r], tmax[r]);
            corr[r] = __expf(m[r] - mn);
            m[r] = mn;
            tsum[r] = 0.f;
        }
#pragma unroll
        for (int n = 0; n < 4; ++n)
#pragma unroll
            for (int r = 0; r < 4; ++r) {
                const float p = __expf(sacc[n][r] * scale - m[r]);
                tsum[r] += p;
                P_lds[wave][lk * 4 + r][n * 16 + lrow] = f2bf(p);
            }
#pragma unroll
        for (int mask = 1; mask <= 8; mask <<= 1)
#pragma unroll
            for (int r = 0; r < 4; ++r)
                tsum[r] += __shfl_xor(tsum[r], mask, 64);
#pragma unroll
        for (int r = 0; r < 4; ++r) l[r] = l[r] * corr[r] + tsum[r];
#pragma unroll
        for (int o = 0; o < 8; ++o)
#pragma unroll
            for (int r = 0; r < 4; ++r) oacc[o][r] *= corr[r];

        // P writes must land before A-fragment reads (same wave, in-order DS)
        asm volatile("s_waitcnt lgkmcnt(0)" ::: "memory");

        // ---- O += P @ V : P(16x64) from LDS, V^T fragments contiguous ----
#pragma unroll
        for (int kc2 = 0; kc2 < 2; ++kc2) {
            const bf16x8 pf = *(const bf16x8*)&P_lds[wave][lrow][kc2 * 32 + lk * 8];
#pragma unroll
            for (int o = 0; o < 8; ++o) {
                const bf16x8 vf = *(const bf16x8*)
                    &Vb[(size_t)(o * 16 + lrow) * S_ + kv0 + kc2 * 32 + lk * 8];
                oacc[o] = __builtin_amdgcn_mfma_f32_16x16x32_bf16(pf, vf, oacc[o], 0, 0, 0);
            }
        }
    }

    // epilogue: normalize by l, store fp32
    float inv[4];
#pragma unroll
    for (int r = 0; r < 4; ++r) inv[r] = 1.f / l[r];
    float* ob = out + ((size_t)b * S_ + q0) * D_;
#pragma unroll
    for (int o = 0; o < 8; ++o)
#pragma unroll
        for (int r = 0; r < 4; ++r)
            ob[(size_t)(lk * 4 + r) * D_ + o * 16 + lrow] = oacc[o][r] * inv[r];
}

// ---------------------------------------------------------------------------
extern "C" void kernel_launch(void* const* d_in, const int* in_sizes, int n_in,
                              void* d_out, int out_size, void* d_ws, size_t ws_size,
                              hipStream_t stream) {
    const float* X  = (const float*)d_in[0];
    const float* Wq = (const float*)d_in[1];
    const float* Wk = (const float*)d_in[2];
    const float* Wv = (const float*)d_in[3];
    float* out = (float*)d_out;

    // workspace: Qw | Kw (row-major bf16) | Vt (transposed bf16) = 12.6 MB
    unsigned short* Qw = (unsigned short*)d_ws;
    unsigned short* Kw = Qw + (size_t)B_ * S_ * D_;
    unsigned short* Vt = Kw + (size_t)B_ * S_ * D_;

    qkv_proj<<<dim3(B_ * S_ / 64), 256, 0, stream>>>(X, Wq, Wk, Wv, Qw, Kw, Vt);
    attn_fwd<<<dim3(S_ / 64, B_), 256, 0, stream>>>(Qw, Kw, Vt, out);
}

// Round 2
// 255.486 us; speedup vs baseline: 1.3454x; 1.3454x over previous
//
#include <hip/hip_runtime.h>
#include <hip/hip_bf16.h>

#define B_ 4
#define S_ 4096
#define D_ 128

typedef __attribute__((ext_vector_type(8))) short bf16x8;   // 8 bf16 in 4 VGPRs
typedef __attribute__((ext_vector_type(4))) float f32x4;

static __device__ __forceinline__ unsigned short f2bf(float f) {
    // round-to-nearest-even float -> bf16
    unsigned int u = __float_as_uint(f);
    unsigned int r = (u + 0x7FFFu + ((u >> 16) & 1u)) >> 16;
    return (unsigned short)r;
}
static __device__ __forceinline__ float bf2f(unsigned short u) {
    return __uint_as_float(((unsigned int)u) << 16);
}

// ---------------------------------------------------------------------------
// Kernel A: QKV projection.  X[16384][128] f32, W[128][128] f32 each.
// Writes Qw,Kw row-major bf16 [16384][128]; Vt transposed bf16 [B][128][4096].
// grid = 256 blocks x 256 threads; each block does 64 rows.
// ---------------------------------------------------------------------------
__global__ __launch_bounds__(256) void qkv_proj(
    const float* __restrict__ X,
    const float* __restrict__ Wq, const float* __restrict__ Wk,
    const float* __restrict__ Wv,
    unsigned short* __restrict__ Qw, unsigned short* __restrict__ Kw,
    unsigned short* __restrict__ Vt)
{
    __shared__ alignas(16) unsigned short Xs[64][136];   // 64 rows x 128 (+8 pad)
    __shared__ alignas(16) unsigned short Wt[128][136];  // W transposed [d_out][d_in]

    const int tid  = threadIdx.x;
    const int wave = tid >> 6, lane = tid & 63;
    const int lrow = lane & 15, lk = lane >> 4;
    const long r0  = (long)blockIdx.x * 64;   // global row base

    // stage X tile -> bf16 LDS (coalesced float4 reads)
    for (int i = tid; i < 2048; i += 256) {
        const int s = i >> 5, c4 = (i & 31) * 4;
        const float4 v = *(const float4*)(X + (r0 + s) * D_ + c4);
        Xs[s][c4 + 0] = f2bf(v.x); Xs[s][c4 + 1] = f2bf(v.y);
        Xs[s][c4 + 2] = f2bf(v.z); Xs[s][c4 + 3] = f2bf(v.w);
    }
    __syncthreads();

    // A-fragments: lane holds X[wave*16 + (lane&15)][kc*32 + (lane>>4)*8 + 0..7]
    bf16x8 af[4];
#pragma unroll
    for (int kc = 0; kc < 4; ++kc)
        af[kc] = *(const bf16x8*)&Xs[wave * 16 + lrow][kc * 32 + lk * 8];

    float vacc[8][4];   // V result parked in registers (Wt LDS gets reused)

#pragma unroll
    for (int w = 0; w < 3; ++w) {
        const float* W = (w == 0) ? Wq : (w == 1) ? Wk : Wv;
        // load W transposed: Wt[d_out][d_in]
        for (int i = tid; i < 16384; i += 256) {
            const int rr = i >> 7, cc = i & 127;
            Wt[cc][rr] = f2bf(W[i]);
        }
        __syncthreads();

#pragma unroll
        for (int nsub = 0; nsub < 8; ++nsub) {
            f32x4 acc = {0.f, 0.f, 0.f, 0.f};
#pragma unroll
            for (int kc = 0; kc < 4; ++kc) {
                const bf16x8 bf = *(const bf16x8*)&Wt[nsub * 16 + lrow][kc * 32 + lk * 8];
                acc = __builtin_amdgcn_mfma_f32_16x16x32_bf16(af[kc], bf, acc, 0, 0, 0);
            }
            if (w < 2) {
                unsigned short* dst = (w == 0) ? Qw : Kw;
#pragma unroll
                for (int r = 0; r < 4; ++r) {
                    const long row = r0 + wave * 16 + lk * 4 + r;
                    dst[row * D_ + nsub * 16 + lrow] = f2bf(acc[r]);
                }
            } else {
#pragma unroll
                for (int r = 0; r < 4; ++r) vacc[nsub][r] = acc[r];
            }
        }
        __syncthreads();   // all waves done reading Wt before reload / reuse
    }

    // V: bounce through LDS (reuse Wt region) for a coalesced transposed store
    unsigned short (*Vs)[136] = Wt;
#pragma unroll
    for (int nsub = 0; nsub < 8; ++nsub)
#pragma unroll
        for (int r = 0; r < 4; ++r)
            Vs[wave * 16 + lk * 4 + r][nsub * 16 + lrow] = f2bf(vacc[nsub][r]);
    __syncthreads();

    const int batch = (int)(r0 >> 12);
    const int sbase = (int)(r0 & 4095);
    const int dd = tid >> 1, sh = (tid & 1) * 32;
    unsigned short* vdst = Vt + (size_t)batch * D_ * S_ + (size_t)dd * S_ + sbase + sh;
    for (int j = 0; j < 32; ++j) vdst[j] = Vs[sh + j][dd];
}

// ---------------------------------------------------------------------------
// Kernel B: flash attention, in-block KV-split.
// grid = (S/64, B), 1024 threads = 16 waves.
// wave w: q-slice (w&3)*16 of the block's 64 rows, KV quarter (w>>2)*1024.
// Partials merged through LDS at the end (bf16 unnormalized O + fp32 m,l).
// ---------------------------------------------------------------------------
__global__ __launch_bounds__(1024) void attn_fwd(
    const unsigned short* __restrict__ Qw, const unsigned short* __restrict__ Kw,
    const unsigned short* __restrict__ Vt, float* __restrict__ out)
{
    // 61440 B aliased region: during loop = per-wave P tiles (16 x 1152 shorts);
    // after barrier = 12 partial slots (2560 shorts each).  +1.5 KB stats.
    __shared__ alignas(16) unsigned short ShBuf[30720];
    __shared__ float Stats[12][16][2];

    const int tid   = threadIdx.x;
    const int wave  = tid >> 6, lane = tid & 63;
    const int lrow  = lane & 15, lk = lane >> 4;
    const int qwave = wave & 3, kgroup = wave >> 2;
    const int b  = blockIdx.y;
    const int q0 = blockIdx.x * 64 + qwave * 16;   // row within batch

    const unsigned short* Qb = Qw + (size_t)b * S_ * D_;
    const unsigned short* Kb = Kw + (size_t)b * S_ * D_;
    const unsigned short* Vb = Vt + (size_t)b * D_ * S_;

    unsigned short* Pl = ShBuf + wave * 1152;      // 16 rows x 72 shorts

    // Q fragments (held for the whole kernel)
    bf16x8 qf[4];
#pragma unroll
    for (int kc = 0; kc < 4; ++kc)
        qf[kc] = *(const bf16x8*)&Qb[(size_t)(q0 + lrow) * D_ + kc * 32 + lk * 8];

    f32x4 oacc[8];
#pragma unroll
    for (int i = 0; i < 8; ++i) oacc[i] = (f32x4){0.f, 0.f, 0.f, 0.f};
    float m[4], l[4];
#pragma unroll
    for (int r = 0; r < 4; ++r) { m[r] = -1e30f; l[r] = 0.f; }

    const float scale = 0.08838834764831845f;   // 1/sqrt(128)
    const int kv_base = kgroup * 1024;

    for (int t = 0; t < 16; ++t) {
        const int kv0 = kv_base + t * 64;
        // ---- S tile = Q @ K^T : 16 q-rows x 64 keys per wave ----
        f32x4 sacc[4];
#pragma unroll
        for (int n = 0; n < 4; ++n) sacc[n] = (f32x4){0.f, 0.f, 0.f, 0.f};
#pragma unroll
        for (int n = 0; n < 4; ++n) {
#pragma unroll
            for (int kc = 0; kc < 4; ++kc) {
                const bf16x8 kf = *(const bf16x8*)
                    &Kb[(size_t)(kv0 + n * 16 + lrow) * D_ + kc * 32 + lk * 8];
                sacc[n] = __builtin_amdgcn_mfma_f32_16x16x32_bf16(qf[kc], kf, sacc[n], 0, 0, 0);
            }
        }
        // ---- online softmax (stats on rows lk*4+r, replicated over 16 lanes) ----
        float tmax[4];
#pragma unroll
        for (int r = 0; r < 4; ++r)
            tmax[r] = fmaxf(fmaxf(sacc[0][r], sacc[1][r]),
                            fmaxf(sacc[2][r], sacc[3][r])) * scale;
#pragma unroll
        for (int mask = 1; mask <= 8; mask <<= 1)
#pragma unroll
            for (int r = 0; r < 4; ++r)
                tmax[r] = fmaxf(tmax[r], __shfl_xor(tmax[r], mask, 64));

        float corr[4], tsum[4];
#pragma unroll
        for (int r = 0; r < 4; ++r) {
            const float mn = fmaxf(m[r], tmax[r]);
            corr[r] = __expf(m[r] - mn);
            m[r] = mn;
            tsum[r] = 0.f;
        }
#pragma unroll
        for (int n = 0; n < 4; ++n)
#pragma unroll
            for (int r = 0; r < 4; ++r) {
                const float p = __expf(sacc[n][r] * scale - m[r]);
                tsum[r] += p;
                Pl[(lk * 4 + r) * 72 + n * 16 + lrow] = f2bf(p);
            }
#pragma unroll
        for (int mask = 1; mask <= 8; mask <<= 1)
#pragma unroll
            for (int r = 0; r < 4; ++r)
                tsum[r] += __shfl_xor(tsum[r], mask, 64);
#pragma unroll
        for (int r = 0; r < 4; ++r) l[r] = l[r] * corr[r] + tsum[r];
#pragma unroll
        for (int o = 0; o < 8; ++o)
#pragma unroll
            for (int r = 0; r < 4; ++r) oacc[o][r] *= corr[r];

        // P writes must land before A-fragment reads (same wave, DS queue)
        asm volatile("s_waitcnt lgkmcnt(0)" ::: "memory");

        // ---- O += P @ V : P(16x64) from LDS, V^T fragments contiguous ----
#pragma unroll
        for (int kc2 = 0; kc2 < 2; ++kc2) {
            const bf16x8 pf = *(const bf16x8*)&Pl[lrow * 72 + kc2 * 32 + lk * 8];
#pragma unroll
            for (int o = 0; o < 8; ++o) {
                const bf16x8 vf = *(const bf16x8*)
                    &Vb[(size_t)(o * 16 + lrow) * S_ + kv0 + kc2 * 32 + lk * 8];
                oacc[o] = __builtin_amdgcn_mfma_f32_16x16x32_bf16(pf, vf, oacc[o], 0, 0, 0);
            }
        }
    }

    // ---- cross-wave combine over the 4 KV groups ----
    __syncthreads();   // everyone done with P region

    if (kgroup > 0) {
        const int s = wave - 4;
        unsigned short* Pp = ShBuf + s * 2560 + lane * 40;  // 80 B/lane, 16B-aligned
#pragma unroll
        for (int c = 0; c < 4; ++c) {
            bf16x8 v;
#pragma unroll
            for (int i = 0; i < 8; ++i) {
                const int idx = c * 8 + i;
                v[i] = (short)f2bf(oacc[idx >> 2][idx & 3]);
            }
            *(bf16x8*)(Pp + c * 8) = v;
        }
        if (lrow == 0) {
#pragma unroll
            for (int r = 0; r < 4; ++r) {
                Stats[s][lk * 4 + r][0] = m[r];
                Stats[s][lk * 4 + r][1] = l[r];
            }
        }
    }
    __syncthreads();

    if (kgroup == 0) {
#pragma unroll
        for (int j = 1; j < 4; ++j) {
            const int s = j * 4 + qwave - 4;
            const unsigned short* Pp = ShBuf + s * 2560 + lane * 40;
            bf16x8 ch[4];
#pragma unroll
            for (int c = 0; c < 4; ++c) ch[c] = *(const bf16x8*)(Pp + c * 8);
            float mj[4], lj[4], a[4], bb[4];
#pragma unroll
            for (int r = 0; r < 4; ++r) {
                mj[r] = Stats[s][lk * 4 + r][0];
                lj[r] = Stats[s][lk * 4 + r][1];
                const float mn = fmaxf(m[r], mj[r]);
                a[r]  = __expf(m[r]  - mn);
                bb[r] = __expf(mj[r] - mn);
                l[r] = l[r] * a[r] + lj[r] * bb[r];
                m[r] = mn;
            }
#pragma unroll
            for (int c = 0; c < 4; ++c)
#pragma unroll
                for (int i = 0; i < 8; ++i) {
                    const int idx = c * 8 + i;
                    const int o = idx >> 2, r = idx & 3;
                    oacc[o][r] = oacc[o][r] * a[r] + bf2f((unsigned short)ch[c][i]) * bb[r];
                }
        }
        // epilogue: normalize by l, store fp32
        float inv[4];
#pragma unroll
        for (int r = 0; r < 4; ++r) inv[r] = 1.f / l[r];
        float* ob = out + ((size_t)b * S_ + q0) * D_;
#pragma unroll
        for (int o = 0; o < 8; ++o)
#pragma unroll
            for (int r = 0; r < 4; ++r)
                ob[(size_t)(lk * 4 + r) * D_ + o * 16 + lrow] = oacc[o][r] * inv[r];
    }
}

// ---------------------------------------------------------------------------
extern "C" void kernel_launch(void* const* d_in, const int* in_sizes, int n_in,
                              void* d_out, int out_size, void* d_ws, size_t ws_size,
                              hipStream_t stream) {
    const float* X  = (const float*)d_in[0];
    const float* Wq = (const float*)d_in[1];
    const float* Wk = (const float*)d_in[2];
    const float* Wv = (const float*)d_in[3];
    float* out = (float*)d_out;

    // workspace: Qw | Kw (row-major bf16) | Vt (transposed bf16) = 12.6 MB
    unsigned short* Qw = (unsigned short*)d_ws;
    unsigned short* Kw = Qw + (size_t)B_ * S_ * D_;
    unsigned short* Vt = Kw + (size_t)B_ * S_ * D_;

    qkv_proj<<<dim3(B_ * S_ / 64), 256, 0, stream>>>(X, Wq, Wk, Wv, Qw, Kw, Vt);
    attn_fwd<<<dim3(S_ / 64, B_), 1024, 0, stream>>>(Qw, Kw, Vt, out);
}